// Round 5
// baseline (603.275 us; speedup 1.0000x reference)
//
#include <hip/hip_runtime.h>

// LSTM RNN_20263655702953 — MI355X (gfx950), round 5.
//
// Reference quirk: hs[:, -1, :] selects BATCH index 511 => single sequential
// LSTM chain (1024 steps, H=64), then (1024,64)@(64,2) projection.
//
// R5: SINGLE WAVE, fully-fused step. R4's counters showed ~500 cyc/step of
// stall structural to the 4-wave gate split (gbuf ds_write->barrier->ds_read
// ~160 cyc + post-barrier update chain before next step's readlanes).
// Now lane l owns unit l and computes ALL FOUR gate rows (l, 64+l, 128+l,
// 192+l; 256 weight VGPRs — fits 512/wave at 1 wave/SIMD). Zero barriers,
// zero LDS h-path, zero exchange: act -> c -> h all lane-local.
// FMA stream is float2 ext-vector => v_pk_fma_f32 (full-rate packed fp32):
// 128 pk-FMA instead of 256 scalar. h broadcast = batched v_readlane
// (R4-proven shape: [RL x16 | pk-FMA x32 + RL x16 | ...] via sched_barrier).
// x consumed AFTER the FMA stream (LDS latency hidden); h history is a
// fire-and-forget coalesced global store per step (no ring, no flush).

typedef float f32x2 __attribute__((ext_vector_type(2)));

#define T_LEN 1024
#define BATCH 512
#define HID   64

__device__ __forceinline__ float fast_rcp(float x) {
    return __builtin_amdgcn_rcpf(x);  // v_rcp_f32, ~1e-7 rel err
}
__device__ __forceinline__ float fast_sigmoid(float x) {
    return fast_rcp(1.0f + __expf(-x));
}
__device__ __forceinline__ float fast_tanh(float x) {
    // 1 - 2/(e^{2x}+1); saturates correctly for |x| large
    return 1.0f - 2.0f * fast_rcp(__expf(2.0f * x) + 1.0f);
}

__global__ __launch_bounds__(64, 1)
void lstm_seq_kernel(const float* __restrict__ x,
                     const float* __restrict__ W_ih,
                     const float* __restrict__ W_hh,
                     const float* __restrict__ b_ih,
                     const float* __restrict__ b_hh,
                     const float* __restrict__ W_fc,
                     const float* __restrict__ b_fc,
                     float* __restrict__ out,
                     float* __restrict__ hist)   // d_ws: 1024*64 floats
{
    __shared__ float xs[2 * T_LEN];   // 8 KB: x[:,511,:]

    const int lane = threadIdx.x;     // 0..63 ; lane l owns hidden unit l

    // ---- stage x[:,511,:] into LDS (one-time; same-wave write->read, no barrier)
    for (int j = 0; j < 16; ++j) {
        const int t = lane + 64 * j;  // 0..1023
        const float2 v = *(const float2*)(x + (size_t)(t * BATCH + (BATCH - 1)) * 2);
        xs[2 * t]     = v.x;
        xs[2 * t + 1] = v.y;
    }

    // ---- preload this lane's FOUR W_hh rows as float2 pairs (256 VGPRs)
    f32x2 w0[32], w1[32], w2[32], w3[32];
    {
        const float4* r0 = (const float4*)(W_hh + (0 * HID + lane) * HID);
        const float4* r1 = (const float4*)(W_hh + (1 * HID + lane) * HID);
        const float4* r2 = (const float4*)(W_hh + (2 * HID + lane) * HID);
        const float4* r3 = (const float4*)(W_hh + (3 * HID + lane) * HID);
        #pragma unroll
        for (int k = 0; k < 16; ++k) {
            float4 v;
            v = r0[k]; w0[2*k] = (f32x2){v.x, v.y}; w0[2*k+1] = (f32x2){v.z, v.w};
            v = r1[k]; w1[2*k] = (f32x2){v.x, v.y}; w1[2*k+1] = (f32x2){v.z, v.w};
            v = r2[k]; w2[2*k] = (f32x2){v.x, v.y}; w2[2*k+1] = (f32x2){v.z, v.w};
            v = r3[k]; w3[2*k] = (f32x2){v.x, v.y}; w3[2*k+1] = (f32x2){v.z, v.w};
        }
    }
    const float wi00 = W_ih[(0 * HID + lane) * 2 + 0], wi01 = W_ih[(0 * HID + lane) * 2 + 1];
    const float wi10 = W_ih[(1 * HID + lane) * 2 + 0], wi11 = W_ih[(1 * HID + lane) * 2 + 1];
    const float wi20 = W_ih[(2 * HID + lane) * 2 + 0], wi21 = W_ih[(2 * HID + lane) * 2 + 1];
    const float wi30 = W_ih[(3 * HID + lane) * 2 + 0], wi31 = W_ih[(3 * HID + lane) * 2 + 1];
    const float bs0 = b_ih[0 * HID + lane] + b_hh[0 * HID + lane];
    const float bs1 = b_ih[1 * HID + lane] + b_hh[1 * HID + lane];
    const float bs2 = b_ih[2 * HID + lane] + b_hh[2 * HID + lane];
    const float bs3 = b_ih[3 * HID + lane] + b_hh[3 * HID + lane];

    float hval = 0.0f;   // lane l holds h[l]
    float cval = 0.0f;   // lane l holds c[l]

    for (int t = 0; t < T_LEN; ++t) {
        // x read issued NOW, consumed after the FMA stream (latency hidden;
        // independent of hval so it doesn't gate the readlanes)
        const float2 xv = *(const float2*)(xs + 2 * t);

        const int hb = __float_as_int(hval);
        f32x2 acc0 = (f32x2){0.0f, 0.0f};
        f32x2 acc1 = acc0, acc2 = acc0, acc3 = acc0;

        int hs[16];
        #pragma unroll
        for (int b = 0; b < 4; ++b) {
            // RL batch b: 16 lane values -> SGPRs
            #pragma unroll
            for (int k = 0; k < 16; ++k)
                hs[k] = __builtin_amdgcn_readlane(hb, 16 * b + k);
            __builtin_amdgcn_sched_barrier(0);
            // pk-FMA batch b (32 v_pk_fma_f32) — compiler interleaves RL b+1
            #pragma unroll
            for (int p = 0; p < 8; ++p) {
                f32x2 hp;
                hp.x = __int_as_float(hs[2 * p]);
                hp.y = __int_as_float(hs[2 * p + 1]);
                const int i = 8 * b + p;
                acc0 += w0[i] * hp;
                acc1 += w1[i] * hp;
                acc2 += w2[i] * hp;
                acc3 += w3[i] * hp;
            }
        }

        // fold bias + x contribution (xv long since arrived)
        float p0 = (acc0.x + acc0.y) + fmaf(wi00, xv.x, fmaf(wi01, xv.y, bs0));
        float p1 = (acc1.x + acc1.y) + fmaf(wi10, xv.x, fmaf(wi11, xv.y, bs1));
        float p2 = (acc2.x + acc2.y) + fmaf(wi20, xv.x, fmaf(wi21, xv.y, bs2));
        float p3 = (acc3.x + acc3.y) + fmaf(wi30, xv.x, fmaf(wi31, xv.y, bs3));

        // 4 independent activation chains (pipelined by the compiler)
        const float gi = fast_sigmoid(p0);
        const float gf = fast_sigmoid(p1);
        const float gg = fast_tanh(p2);
        const float go = fast_sigmoid(p3);

        cval = fmaf(gf, cval, gi * gg);
        hval = go * fast_tanh(cval);

        // h history: fire-and-forget coalesced store (drains off-path)
        hist[t * HID + lane] = hval;
    }

    // ---- projection: out[t,o] = b_fc[o] + dot(W_fc[o,:], hist[t,:])
    // same-wave store->load on hist: compiler inserts the vmcnt drain.
    for (int j = 0; j < 32; ++j) {
        const int idx = lane + 64 * j;      // 0..2047
        const int t   = idx >> 1;
        const int o   = idx & 1;
        const float4* hv4 = (const float4*)(hist + t * HID);
        const float4* wv  = (const float4*)(W_fc + o * HID);
        float p0 = 0.f, p1 = 0.f, p2 = 0.f, p3 = 0.f;
        #pragma unroll
        for (int k = 0; k < HID / 4; ++k) {
            float4 h4 = hv4[k], w4 = wv[k];
            p0 = fmaf(h4.x, w4.x, p0);
            p1 = fmaf(h4.y, w4.y, p1);
            p2 = fmaf(h4.z, w4.z, p2);
            p3 = fmaf(h4.w, w4.w, p3);
        }
        out[idx] = b_fc[o] + ((p0 + p1) + (p2 + p3));
    }
}

extern "C" void kernel_launch(void* const* d_in, const int* in_sizes, int n_in,
                              void* d_out, int out_size, void* d_ws, size_t ws_size,
                              hipStream_t stream) {
    const float* x    = (const float*)d_in[0];
    const float* W_ih = (const float*)d_in[1];
    const float* W_hh = (const float*)d_in[2];
    const float* b_ih = (const float*)d_in[3];
    const float* b_hh = (const float*)d_in[4];
    const float* W_fc = (const float*)d_in[5];
    const float* b_fc = (const float*)d_in[6];
    float* out  = (float*)d_out;
    float* hist = (float*)d_ws;   // needs 1024*64*4 = 256 KB

    lstm_seq_kernel<<<dim3(1), dim3(64), 0, stream>>>(
        x, W_ih, W_hh, b_ih, b_hh, W_fc, b_fc, out, hist);
}

// Round 6
// 486.417 us; speedup vs baseline: 1.2402x; 1.2402x over previous
//
#include <hip/hip_runtime.h>

// LSTM RNN_20263655702953 — MI355X (gfx950), round 6.
//
// Reference quirk: hs[:, -1, :] selects BATCH index 511 => single sequential
// LSTM chain (1024 steps, H=64), then (1024,64)@(64,2) projection.
//
// R6: k-transposed 4-wave split. Lessons: readlane ~4cyc, pk_fma_f32 4cyc
// (fp32 VALU = 256 FLOP/cyc/CU hard cap), so R4/R5 were ISSUE-bound on the
// 64-lane broadcast. New split: wave w owns k-quarter AND units [16w,16w+16).
// Lane l = 4*ul+s computes partial gates (i,f,g,o) of unit l over k in
// [16w,16w+16): only 16 readlanes (of its OWN wave's h) + 64 FMA.
// Exchange: one ds_write_b128 of packed partials -> barrier -> each lane
// reads slot s of its unit -> quad-DPP 2-round add (VALU-speed reduce).
// Result: all 4 gates of unit 16w+ul in lane 4*ul+s => act/c/h lane-local,
// h for next step's readlanes already wave-local. ONE barrier per step,
// zero h-exchange, no redundant LDS traffic.

#define T_LEN 1024
#define BATCH 512
#define HID   64

__device__ __forceinline__ float fast_rcp(float x) {
    return __builtin_amdgcn_rcpf(x);  // v_rcp_f32, ~1e-7 rel err
}
__device__ __forceinline__ float fast_sigmoid(float x) {
    return fast_rcp(1.0f + __expf(-x));
}
__device__ __forceinline__ float fast_tanh(float x) {
    // 1 - 2/(e^{2x}+1); saturates correctly for |x| large
    return 1.0f - 2.0f * fast_rcp(__expf(2.0f * x) + 1.0f);
}
// quad-local butterfly adds via DPP (full-rate VALU cross-lane, no LDS)
__device__ __forceinline__ float dpp_add_xor1(float v) {
    int t = __builtin_amdgcn_update_dpp(0, __float_as_int(v), 0xB1, 0xF, 0xF, true); // quad_perm [1,0,3,2]
    return v + __int_as_float(t);
}
__device__ __forceinline__ float dpp_add_xor2(float v) {
    int t = __builtin_amdgcn_update_dpp(0, __float_as_int(v), 0x4E, 0xF, 0xF, true); // quad_perm [2,3,0,1]
    return v + __int_as_float(t);
}

__global__ __launch_bounds__(256, 1)
void lstm_seq_kernel(const float* __restrict__ x,
                     const float* __restrict__ W_ih,
                     const float* __restrict__ W_hh,
                     const float* __restrict__ b_ih,
                     const float* __restrict__ b_hh,
                     const float* __restrict__ W_fc,
                     const float* __restrict__ b_fc,
                     float* __restrict__ out,
                     float* __restrict__ hist)   // d_ws: 1024*64 floats
{
    __shared__ float  xs[2 * T_LEN];        // 8 KB: x[:,511,:]
    __shared__ float4 pbuf[2][4][64];       // 8 KB: dbuf partials [buf][kwave][unit]
    __shared__ float  hring[64 * HID];      // 16 KB: ring of last 64 h vectors

    const int tid  = threadIdx.x;
    const int lane = tid & 63;
    const int wv   = tid >> 6;              // wave id = k-quarter = unit-block
    const int s    = lane & 3;              // partial slot this lane reduces
    const int ul   = lane >> 2;             // unit-local index
    const int u0   = 16 * wv + ul;          // unit owned by this lane (quad-replicated)

    // ---- stage x[:,511,:] into LDS (one-time)
    for (int j = 0; j < 4; ++j) {
        const int t = tid + 256 * j;        // 0..1023
        const float2 v = *(const float2*)(x + (size_t)(t * BATCH + (BATCH - 1)) * 2);
        xs[2 * t]     = v.x;
        xs[2 * t + 1] = v.y;
    }

    // ---- weights: lane l handles rows g*64+lane over k in [16*wv, 16*wv+16)
    float w0[16], w1[16], w2[16], w3[16];
    {
        const float* b0 = W_hh + (0 * HID + lane) * HID + 16 * wv;
        const float* b1 = W_hh + (1 * HID + lane) * HID + 16 * wv;
        const float* b2 = W_hh + (2 * HID + lane) * HID + 16 * wv;
        const float* b3 = W_hh + (3 * HID + lane) * HID + 16 * wv;
        #pragma unroll
        for (int q = 0; q < 4; ++q) {
            float4 v;
            v = ((const float4*)b0)[q]; w0[4*q]=v.x; w0[4*q+1]=v.y; w0[4*q+2]=v.z; w0[4*q+3]=v.w;
            v = ((const float4*)b1)[q]; w1[4*q]=v.x; w1[4*q+1]=v.y; w1[4*q+2]=v.z; w1[4*q+3]=v.w;
            v = ((const float4*)b2)[q]; w2[4*q]=v.x; w2[4*q+1]=v.y; w2[4*q+2]=v.z; w2[4*q+3]=v.w;
            v = ((const float4*)b3)[q]; w3[4*q]=v.x; w3[4*q+1]=v.y; w3[4*q+2]=v.z; w3[4*q+3]=v.w;
        }
    }
    // bias + x-weights folded into wave 0's partial only (zeros elsewhere)
    float bs0=0, bs1=0, bs2=0, bs3=0, wa0=0, wa1=0, wa2=0, wa3=0, wb0=0, wb1=0, wb2=0, wb3=0;
    if (wv == 0) {
        bs0 = b_ih[0*HID+lane] + b_hh[0*HID+lane];
        bs1 = b_ih[1*HID+lane] + b_hh[1*HID+lane];
        bs2 = b_ih[2*HID+lane] + b_hh[2*HID+lane];
        bs3 = b_ih[3*HID+lane] + b_hh[3*HID+lane];
        wa0 = W_ih[(0*HID+lane)*2]; wb0 = W_ih[(0*HID+lane)*2+1];
        wa1 = W_ih[(1*HID+lane)*2]; wb1 = W_ih[(1*HID+lane)*2+1];
        wa2 = W_ih[(2*HID+lane)*2]; wb2 = W_ih[(2*HID+lane)*2+1];
        wa3 = W_ih[(3*HID+lane)*2]; wb3 = W_ih[(3*HID+lane)*2+1];
    }

    float hval = 0.0f;   // h[u0] (quad-replicated within the wave)
    float cval = 0.0f;   // c[u0]

    __syncthreads();

    for (int t = 0; t < T_LEN; ++t) {
        // ---- partial gates over this wave's k-quarter
        const float2 xv = *(const float2*)(xs + 2 * t);   // uniform bcast
        const int hb = __float_as_int(hval);
        float hs[16];
        #pragma unroll
        for (int j = 0; j < 16; ++j)                      // h[16*wv + j]
            hs[j] = __int_as_float(__builtin_amdgcn_readlane(hb, 4 * j));
        __builtin_amdgcn_sched_barrier(0);

        float a0 = fmaf(wa0, xv.x, fmaf(wb0, xv.y, bs0)); // zeros for wv!=0
        float a1 = fmaf(wa1, xv.x, fmaf(wb1, xv.y, bs1));
        float a2 = fmaf(wa2, xv.x, fmaf(wb2, xv.y, bs2));
        float a3 = fmaf(wa3, xv.x, fmaf(wb3, xv.y, bs3));
        #pragma unroll
        for (int k = 0; k < 16; ++k) {
            const float hk = hs[k];
            a0 = fmaf(w0[k], hk, a0);
            a1 = fmaf(w1[k], hk, a1);
            a2 = fmaf(w2[k], hk, a2);
            a3 = fmaf(w3[k], hk, a3);
        }

        // ---- exchange: packed partial per (kwave, unit)
        const int buf = t & 1;
        pbuf[buf][wv][lane] = make_float4(a0, a1, a2, a3);
        __syncthreads();                    // the only per-step barrier

        float4 ps = pbuf[buf][s][u0];       // slot s of my unit
        // quad reduce: sum the 4 k-quarters (all quad lanes end with total)
        ps.x = dpp_add_xor2(dpp_add_xor1(ps.x));
        ps.y = dpp_add_xor2(dpp_add_xor1(ps.y));
        ps.z = dpp_add_xor2(dpp_add_xor1(ps.z));
        ps.w = dpp_add_xor2(dpp_add_xor1(ps.w));

        // ---- lane-local activation + state update (4x quad-redundant)
        const float gi = fast_sigmoid(ps.x);
        const float gf = fast_sigmoid(ps.y);
        const float gg = fast_tanh(ps.z);
        const float go = fast_sigmoid(ps.w);
        cval = fmaf(gf, cval, gi * gg);
        hval = go * fast_tanh(cval);

        // ---- h history ring (LDS write off the critical chain)
        if (s == 0) hring[(t & 63) * HID + u0] = hval;

        if ((t & 63) == 63) {               // uniform; amortized /64
            __syncthreads();                // ring writes visible
            float4*       dst = (float4*)(hist + (t - 63) * HID);
            const float4* src = (const float4*)hring;
            #pragma unroll
            for (int j = 0; j < 4; ++j)     // 4096 floats, coalesced
                dst[tid + 256 * j] = src[tid + 256 * j];
            __syncthreads();                // flush reads done before ring reuse
        }
    }

    __syncthreads();  // final flush drained & visible

    // ---- projection: out[t,o] = b_fc[o] + dot(W_fc[o,:], hist[t,:])
    #pragma unroll
    for (int j = 0; j < 8; ++j) {
        const int idx = tid + j * 256;      // 0..2047, coalesced stores
        const int t   = idx >> 1;
        const int o   = idx & 1;
        const float4* hv4 = (const float4*)(hist + t * HID);
        const float4* wvv = (const float4*)(W_fc + o * HID);
        float p0 = 0.f, p1 = 0.f, p2 = 0.f, p3 = 0.f;
        #pragma unroll
        for (int k = 0; k < HID / 4; ++k) {
            float4 h4 = hv4[k], w4 = wvv[k];
            p0 = fmaf(h4.x, w4.x, p0);
            p1 = fmaf(h4.y, w4.y, p1);
            p2 = fmaf(h4.z, w4.z, p2);
            p3 = fmaf(h4.w, w4.w, p3);
        }
        out[idx] = b_fc[o] + ((p0 + p1) + (p2 + p3));
    }
}

extern "C" void kernel_launch(void* const* d_in, const int* in_sizes, int n_in,
                              void* d_out, int out_size, void* d_ws, size_t ws_size,
                              hipStream_t stream) {
    const float* x    = (const float*)d_in[0];
    const float* W_ih = (const float*)d_in[1];
    const float* W_hh = (const float*)d_in[2];
    const float* b_ih = (const float*)d_in[3];
    const float* b_hh = (const float*)d_in[4];
    const float* W_fc = (const float*)d_in[5];
    const float* b_fc = (const float*)d_in[6];
    float* out  = (float*)d_out;
    float* hist = (float*)d_ws;   // needs 1024*64*4 = 256 KB

    lstm_seq_kernel<<<dim3(1), dim3(256), 0, stream>>>(
        x, W_ih, W_hh, b_ih, b_hh, W_fc, b_fc, out, hist);
}